// Round 4
// baseline (301.084 us; speedup 1.0000x reference)
//
#include <hip/hip_runtime.h>

typedef _Float16 half8 __attribute__((ext_vector_type(8)));
typedef float f16v __attribute__((ext_vector_type(16)));
typedef float f4 __attribute__((ext_vector_type(4)));
typedef unsigned long long ull;

#define X_SLAB   1048576            // 32^4
#define PLANE_F16 (34*36*4)         // one (j1,j2) plane: [j3<34][j4<36][t<4]
#define PLANE_BYTES (PLANE_F16*2)   // 9792
#define RPT_SITES (34*34*34*36)     // 1,414,944 sites (8B each)
#define RPT_OFF  32768              // byte offset of rp_t in ws
#define TAB_ELEMS  (4*81*8)         // fp32 fallback table

// ---------------------------------------------------------------------------
// prep_tab: B-operand table for mfma_f32_32x32x16_f16.
// tabm[slice][lane][j] , slice=(p2*3+p3)*3+p4 , k=8*(lane>>5)+j , n=lane&31.
// k = p5hat*4 + t (p5hat==3 or n>=8 -> 0).
// branch0: w[a',b',p2,p3,p4,p5]; branch1: w[b',a',p4,p5,p2,p3];
// a'=t1-s1+1, b'=t2-s2+1, n=(s1*2+s2)*2+branch.
// ---------------------------------------------------------------------------
__global__ void prep_tab(const float* __restrict__ w, _Float16* __restrict__ tabm) {
    int idx = blockIdx.x * 256 + threadIdx.x;       // 27*64*8 = 13824
    if (idx >= 27*512) return;
    int j = idx & 7, l = (idx >> 3) & 63, slice = idx >> 9;
    int k = 8*(l>>5) + j;
    int n = l & 31;
    int p5h = k >> 2, t = k & 3;
    float val = 0.f;
    if (n < 8 && p5h < 3) {
        int p4 = slice % 3, p3 = (slice/3) % 3, p2 = slice/9;
        int br = n & 1, s = n >> 1, s1 = s >> 1, s2 = s & 1;
        int t1 = t >> 1, t2 = t & 1;
        int a = t1 - s1 + 1, b = t2 - s2 + 1;
        int widx = (br == 0)
            ? (a*243 + b*81 + p2*27 + p3*9 + p4*3 + p5h)
            : (b*243 + a*81 + p4*27 + p5h*9 + p2*3 + p3);
        val = w[widx];
    }
    tabm[idx] = (_Float16)val;
}

// ---------------------------------------------------------------------------
// prep_rpt: t-innermost padded relu array. rpt site (j1,j2,j3,j4) holds
// {relu(x[t][j-1])}_{t=0..3} as 4 f16 (8B); zero in halo/padding.
// dims: j1,j2,j3 in [0,34), j4 in [0,36).
// ---------------------------------------------------------------------------
__global__ __launch_bounds__(256)
void prep_rpt(const float* __restrict__ x, ull* __restrict__ rpt) {
    unsigned s = blockIdx.x * 256 + threadIdx.x;
    if (s >= RPT_SITES) return;
    unsigned q = s;
    int j4 = q % 36; q /= 36;
    int j3 = q % 34; q /= 34;
    int j2 = q % 34; q /= 34;
    int j1 = q;
    union { _Float16 h[4]; ull u; } pk;
    pk.u = 0ull;
    if (j1 >= 1 && j1 <= 32 && j2 >= 1 && j2 <= 32 &&
        j3 >= 1 && j3 <= 32 && j4 >= 1 && j4 <= 32) {
        size_t off = (size_t)(j1-1)*32768 + (j2-1)*1024 + (j3-1)*32 + (j4-1);
        #pragma unroll
        for (int t = 0; t < 4; ++t)
            pk.h[t] = (_Float16)fmaxf(x[(size_t)t*X_SLAB + off], 0.f);
    }
    rpt[s] = pk.u;
}

// ---------------------------------------------------------------------------
// conv_mfma: block = (e2,e1); 1024 points; wave w owns e3-rows 8w..8w+7.
// Per (p2,p3): stage plane into LDS; j3-loop: one A-frag load feeds the
// three p4 MFMAs (acc row r = j3l - p4).
// ---------------------------------------------------------------------------
__global__ __launch_bounds__(256)
void conv_mfma(const float* __restrict__ x, const _Float16* __restrict__ rpt,
               const _Float16* __restrict__ tabm, float* __restrict__ out) {
    __shared__ f4 plane4[612];                 // 9792 B
    __shared__ unsigned char msk[1024];
    __shared__ float obuf[1024];
    _Float16* planeh = (_Float16*)plane4;

    const int tid  = threadIdx.x;
    const int lane = tid & 63;
    const int wv   = tid >> 6;                 // 0..3
    const int e2 = blockIdx.x, e1 = blockIdx.y;
    const size_t blockbase = (size_t)e1*32768 + (size_t)e2*1024;

    // mask nibbles: bit i = (x[i][pt] != 0)
    {
        int p = tid * 4;
        f4 a0 = *(const f4*)(x + 0*(size_t)X_SLAB + blockbase + p);
        f4 a1 = *(const f4*)(x + 1*(size_t)X_SLAB + blockbase + p);
        f4 a2 = *(const f4*)(x + 2*(size_t)X_SLAB + blockbase + p);
        f4 a3 = *(const f4*)(x + 3*(size_t)X_SLAB + blockbase + p);
        #pragma unroll
        for (int q = 0; q < 4; ++q) {
            unsigned b = (a0[q] != 0.f ? 1u : 0u) | (a1[q] != 0.f ? 2u : 0u)
                       | (a2[q] != 0.f ? 4u : 0u) | (a3[q] != 0.f ? 8u : 0u);
            msk[p + q] = (unsigned char)b;
        }
    }

    f16v acc[8];
    #pragma unroll
    for (int r = 0; r < 8; ++r)
        #pragma unroll
        for (int i = 0; i < 16; ++i) acc[r][i] = 0.f;

    const int R   = wv * 8;
    const int j4b = (lane & 31) + 2*(lane >> 5);   // A-frag site base

    #pragma unroll 1
    for (int p2 = 0; p2 < 3; ++p2) {
        #pragma unroll 1
        for (int p3 = 0; p3 < 3; ++p3) {
            const f4* pg = (const f4*)((const char*)rpt
                         + ((size_t)(e1+p2)*34 + (e2+p3)) * PLANE_BYTES);
            __syncthreads();
            #pragma unroll
            for (int kk = 0; kk < 3; ++kk) {
                int idx = tid + kk*256;
                if (idx < 612) plane4[idx] = pg[idx];
            }
            __syncthreads();

            const int sb = ((p2*3 + p3)*3) * 512;
            half8 B0 = *(const half8*)(tabm + sb          + lane*8);
            half8 B1 = *(const half8*)(tabm + sb +  512   + lane*8);
            half8 B2 = *(const half8*)(tabm + sb + 1024   + lane*8);

            #pragma unroll
            for (int j3l = 0; j3l < 10; ++j3l) {
                const ull* ap = (const ull*)(planeh + ((R + j3l)*36 + j4b)*4);
                union { ull u[2]; half8 h; } A;
                A.u[0] = ap[0]; A.u[1] = ap[1];
                if (j3l <= 7)
                    acc[j3l]   = __builtin_amdgcn_mfma_f32_32x32x16_f16(A.h, B0, acc[j3l],   0,0,0);
                if (j3l >= 1 && j3l <= 8)
                    acc[j3l-1] = __builtin_amdgcn_mfma_f32_32x32x16_f16(A.h, B1, acc[j3l-1], 0,0,0);
                if (j3l >= 2)
                    acc[j3l-2] = __builtin_amdgcn_mfma_f32_32x32x16_f16(A.h, B2, acc[j3l-2], 0,0,0);
            }
        }
    }

    // epilogue: D col = lane&31 (= n), row m = (reg&3)+8*(reg>>2)+4*(lane>>5)
    const int n = lane & 31;
    const int mb4 = 4*(lane >> 5);
    #pragma unroll 1
    for (int rloc = 0; rloc < 8; ++rloc) {
        int e3 = R + rloc;
        #pragma unroll
        for (int reg = 0; reg < 16; ++reg) {
            int m = (reg & 3) + 8*(reg >> 2) + mb4;
            float a = acc[rloc][reg];
            float sig = __builtin_amdgcn_rcpf(1.f + __expf(-a));
            float term = 0.f;
            if (n < 8) {
                unsigned mbits = msk[e3*32 + m];
                term = ((mbits >> (n >> 1)) & 1u) ? sig : 0.f;
            }
            term += __shfl_xor(term, 1);
            term += __shfl_xor(term, 2);
            term += __shfl_xor(term, 4);
            if (n == 0) obuf[e3*32 + m] = term;
        }
    }
    __syncthreads();
    {
        int p = tid * 4;
        *(f4*)(out + blockbase + p) = *(const f4*)(obuf + p);
    }
}

// ---------------------------------------------------------------------------
// fp32 fallback (ws too small): known-good from round 1.
// ---------------------------------------------------------------------------
__global__ void build_wtab(const float* __restrict__ w, float* __restrict__ tab) {
    int idx = blockIdx.x * blockDim.x + threadIdx.x;
    if (idx >= TAB_ELEMS) return;
    int n  = idx & 7;
    int r  = idx >> 3;
    int p5 = r % 3; r /= 3;
    int p4 = r % 3; r /= 3;
    int p3 = r % 3; r /= 3;
    int p2 = r % 3; r /= 3;
    int t  = r;
    int t1 = t >> 1, t2 = t & 1;
    int br = n & 1;
    int s  = n >> 1;
    int s1 = s >> 1, s2 = s & 1;
    int a = t1 - s1 + 1;
    int b = t2 - s2 + 1;
    int widx = (br == 0)
        ? (a*243 + b*81 + p2*27 + p3*9 + p4*3 + p5)
        : (b*243 + a*81 + p4*27 + p5*9 + p2*3 + p3);
    tab[idx] = w[widx];
}

__global__ __launch_bounds__(256)
void conv_fp32(const float* __restrict__ x,
               const float* __restrict__ tab,
               float* __restrict__ out) {
    const int e4 = threadIdx.x;
    const int e3 = blockIdx.x * 8 + threadIdx.y;
    const int e2 = blockIdx.y;
    const int e1 = blockIdx.z;

    float acc[8];
    #pragma unroll
    for (int n = 0; n < 8; ++n) acc[n] = 0.f;

    #pragma unroll 1
    for (int t = 0; t < 4; ++t) {
        const float* st  = x + (size_t)t * X_SLAB;
        const float* wt0 = tab + t * 648;
        #pragma unroll
        for (int p2 = 0; p2 < 3; ++p2) {
            #pragma unroll
            for (int p3 = 0; p3 < 3; ++p3) {
                int i1 = e1 + p2 - 1, i2 = e2 + p3 - 1;
                bool v12 = ((unsigned)i1 < 32u) && ((unsigned)i2 < 32u);
                const float* base = st + (i1*32768 + i2*1024 + (e3-1)*32 + (e4-1));
                const float* wt = wt0 + (p2*3 + p3) * 72;
                #pragma unroll
                for (int p4 = 0; p4 < 3; ++p4) {
                    int i3 = e3 + p4 - 1;
                    bool v3 = v12 && ((unsigned)i3 < 32u);
                    #pragma unroll
                    for (int p5 = 0; p5 < 3; ++p5) {
                        int i4 = e4 + p5 - 1;
                        bool ok = v3 && ((unsigned)i4 < 32u);
                        float v = ok ? fmaxf(base[p4*32 + p5], 0.f) : 0.f;
                        const float* w8 = wt + (p4*3 + p5)*8;
                        #pragma unroll
                        for (int n = 0; n < 8; ++n)
                            acc[n] = fmaf(w8[n], v, acc[n]);
                    }
                }
            }
        }
    }

    const size_t eflat = (size_t)e1*32768 + e2*1024 + e3*32 + e4;
    float res = 0.f;
    #pragma unroll
    for (int i = 0; i < 4; ++i) {
        float xv = x[(size_t)i * X_SLAB + eflat];
        float s0 = __builtin_amdgcn_rcpf(1.f + __expf(-acc[2*i]));
        float s1 = __builtin_amdgcn_rcpf(1.f + __expf(-acc[2*i+1]));
        float m  = (xv != 0.f) ? 1.f : 0.f;
        res = fmaf(m, s0 + s1, res);
    }
    out[eflat] = res;
}

// ---------------------------------------------------------------------------
extern "C" void kernel_launch(void* const* d_in, const int* in_sizes, int n_in,
                              void* d_out, int out_size, void* d_ws, size_t ws_size,
                              hipStream_t stream) {
    const float* x = (const float*)d_in[0];    // (1,2,2,32,32,32,32) fp32
    const float* w = (const float*)d_in[1];    // (729,) fp32
    float* out = (float*)d_out;                // (1,32,32,32,32) fp32

    const size_t need = (size_t)RPT_OFF + (size_t)RPT_SITES * 8ull;  // ~11.35 MB

    if (ws_size >= need) {
        _Float16* tabm = (_Float16*)d_ws;                     // 27648 B
        ull*      rpt  = (ull*)((char*)d_ws + RPT_OFF);
        prep_tab<<<dim3(54), dim3(256), 0, stream>>>(w, tabm);
        prep_rpt<<<dim3((RPT_SITES + 255)/256), dim3(256), 0, stream>>>(x, rpt);
        dim3 grd(32, 32, 1), blk(256, 1, 1);
        conv_mfma<<<grd, blk, 0, stream>>>(x, (const _Float16*)rpt, tabm, out);
    } else {
        float* tab = (float*)d_ws;
        build_wtab<<<dim3((TAB_ELEMS + 255)/256), dim3(256), 0, stream>>>(w, tab);
        dim3 blk(32, 8, 1), grd(4, 32, 32);
        conv_fp32<<<grd, blk, 0, stream>>>(x, tab, out);
    }
}

// Round 5
// 106.832 us; speedup vs baseline: 2.8183x; 2.8183x over previous
//
#include <hip/hip_runtime.h>

typedef _Float16 half8 __attribute__((ext_vector_type(8)));
typedef float f16v __attribute__((ext_vector_type(16)));
typedef float f4 __attribute__((ext_vector_type(4)));
typedef unsigned long long ull;

#define X_SLAB   1048576            // 32^4
#define PLANE_BYTES (34*36*4*2)     // 9792: one (j1,j2) plane [j3<34][j4<36][t<4] f16
#define RPT_SITES (34*34*34*36)     // 1,414,944 sites (8B each)
#define RPT_OFF  32768              // byte offset of rp_t in ws
#define RPT_SLACK 4096              // DMA tail overrun slack
#define TAB_ELEMS  (4*81*8)         // fp32 fallback table
#define OB_STRIDE 1032              // obuf row stride (floats): 8n%32 -> 2-way only

// ---------------------------------------------------------------------------
// prep: t-innermost padded relu f16 array; block 0 also builds the MFMA
// B-operand table.
// rpt site (j1,j2,j3,j4) holds {relu(x[t][j-1])}_{t=0..3} (8B), zero in halo.
// tabm[slice][lane][j], slice=(p2*3+p3)*3+p4, k=8*(lane>>5)+j, n=lane&31,
// k=p5h*4+t (p5h==3 or n>=8 -> 0).
// branch0: w[a',b',p2,p3,p4,p5]; branch1: w[b',a',p4,p5,p2,p3];
// a'=t1-s1+1, b'=t2-s2+1, n=(s1*2+s2)*2+branch.
// ---------------------------------------------------------------------------
__global__ __launch_bounds__(256)
void prep(const float* __restrict__ x, const float* __restrict__ w,
          ull* __restrict__ rpt, _Float16* __restrict__ tabm) {
    unsigned s = blockIdx.x * 256 + threadIdx.x;
    if (s < RPT_SITES) {
        unsigned q = s;
        int j4 = q % 36; q /= 36;
        int j3 = q % 34; q /= 34;
        int j2 = q % 34; q /= 34;
        int j1 = q;
        union { _Float16 h[4]; ull u; } pk;
        pk.u = 0ull;
        if (j1 >= 1 && j1 <= 32 && j2 >= 1 && j2 <= 32 &&
            j3 >= 1 && j3 <= 32 && j4 >= 1 && j4 <= 32) {
            size_t off = (size_t)(j1-1)*32768 + (j2-1)*1024 + (j3-1)*32 + (j4-1);
            #pragma unroll
            for (int t = 0; t < 4; ++t)
                pk.h[t] = (_Float16)fmaxf(x[(size_t)t*X_SLAB + off], 0.f);
        }
        rpt[s] = pk.u;
    }
    if (blockIdx.x == 0) {
        for (int idx = threadIdx.x; idx < 27*512; idx += 256) {
            int j = idx & 7, l = (idx >> 3) & 63, slice = idx >> 9;
            int k = 8*(l>>5) + j;
            int n = l & 31;
            int p5h = k >> 2, t = k & 3;
            float val = 0.f;
            if (n < 8 && p5h < 3) {
                int p4 = slice % 3, p3 = (slice/3) % 3, p2 = slice/9;
                int br = n & 1, sc = n >> 1, s1 = sc >> 1, s2 = sc & 1;
                int t1 = t >> 1, t2 = t & 1;
                int a = t1 - s1 + 1, b = t2 - s2 + 1;
                int widx = (br == 0)
                    ? (a*243 + b*81 + p2*27 + p3*9 + p4*3 + p5h)
                    : (b*243 + a*81 + p4*27 + p5h*9 + p2*3 + p3);
                val = w[widx];
            }
            tabm[idx] = (_Float16)val;
        }
    }
}

// ---------------------------------------------------------------------------
// conv_mfma: block = (e2,e1); 1024 points; wave wv owns e3-rows 8wv..8wv+7.
// Per (p2,p3): DMA-stage plane into LDS (global_load_lds x16B); j3 sliding
// window: one A-frag load feeds the three p4 MFMAs (acc row r = j3l - p4).
// Epilogue: useful cols restaged to obuf[n][point] (overlays plane), then
// per-point sigmoid+mask reduce.
// ---------------------------------------------------------------------------
__global__ __launch_bounds__(256)
void conv_mfma(const float* __restrict__ x, const ull* __restrict__ rpt,
               const _Float16* __restrict__ tabm, float* __restrict__ out) {
    __shared__ __align__(16) unsigned char arena[34048];
    _Float16* planeh = (_Float16*)arena;          // [0, 12288) staged plane
    float*    obuf   = (float*)arena;             // [0, 33024) overlay (epilogue)
    unsigned char* msk = arena + 33024;           // [33024, 34048)

    const int tid  = threadIdx.x;
    const int lane = tid & 63;
    const int wv   = tid >> 6;                 // 0..3
    const int e2 = blockIdx.x, e1 = blockIdx.y;
    const size_t blockbase = (size_t)e1*32768 + (size_t)e2*1024;

    // mask nibbles: bit i = (x[i][pt] != 0)
    {
        int p = tid * 4;
        f4 a0 = *(const f4*)(x + 0*(size_t)X_SLAB + blockbase + p);
        f4 a1 = *(const f4*)(x + 1*(size_t)X_SLAB + blockbase + p);
        f4 a2 = *(const f4*)(x + 2*(size_t)X_SLAB + blockbase + p);
        f4 a3 = *(const f4*)(x + 3*(size_t)X_SLAB + blockbase + p);
        #pragma unroll
        for (int q = 0; q < 4; ++q) {
            unsigned b = (a0[q] != 0.f ? 1u : 0u) | (a1[q] != 0.f ? 2u : 0u)
                       | (a2[q] != 0.f ? 4u : 0u) | (a3[q] != 0.f ? 8u : 0u);
            msk[p + q] = (unsigned char)b;
        }
    }

    f16v acc[8];
    #pragma unroll
    for (int r = 0; r < 8; ++r)
        #pragma unroll
        for (int i = 0; i < 16; ++i) acc[r][i] = 0.f;

    const int R   = wv * 8;
    const int j4b = (lane & 31) + 2*(lane >> 5);   // A-frag site base

    #pragma unroll 1
    for (int p2 = 0; p2 < 3; ++p2) {
        #pragma unroll 1
        for (int p3 = 0; p3 < 3; ++p3) {
            const char* pgb = (const char*)rpt
                            + ((size_t)(e1+p2)*34 + (e2+p3)) * PLANE_BYTES;
            __syncthreads();   // previous plane reads done before overwrite
            #pragma unroll
            for (int kk = 0; kk < 3; ++kk) {       // 3*4096B = 12288B staged
                int off = (tid + kk*256) * 16;
                __builtin_amdgcn_global_load_lds(
                    (const __attribute__((address_space(1))) unsigned int*)(pgb + off),
                    (__attribute__((address_space(3))) unsigned int*)(arena + off),
                    16, 0, 0);
            }
            __syncthreads();   // drains vmcnt before barrier (m97 pattern)

            const int sb = ((p2*3 + p3)*3) * 512;
            half8 B0 = *(const half8*)(tabm + sb          + lane*8);
            half8 B1 = *(const half8*)(tabm + sb +  512   + lane*8);
            half8 B2 = *(const half8*)(tabm + sb + 1024   + lane*8);

            #pragma unroll
            for (int j3l = 0; j3l < 10; ++j3l) {
                const ull* ap = (const ull*)(planeh + ((R + j3l)*36 + j4b)*4);
                union { ull u[2]; half8 h; } A;
                A.u[0] = ap[0]; A.u[1] = ap[1];
                if (j3l <= 7)
                    acc[j3l]   = __builtin_amdgcn_mfma_f32_32x32x16_f16(A.h, B0, acc[j3l],   0,0,0);
                if (j3l >= 1 && j3l <= 8)
                    acc[j3l-1] = __builtin_amdgcn_mfma_f32_32x32x16_f16(A.h, B1, acc[j3l-1], 0,0,0);
                if (j3l >= 2)
                    acc[j3l-2] = __builtin_amdgcn_mfma_f32_32x32x16_f16(A.h, B2, acc[j3l-2], 0,0,0);
            }
        }
    }

    // ---- epilogue ----
    // D layout (verified): col n = lane&31, row m = (reg&3)+8*(reg>>2)+4*(lane>>5)
    __syncthreads();           // all A-reads done; obuf may overwrite plane
    {
        const int n   = lane & 31;
        const int mb4 = 4*(lane >> 5);
        if (n < 8) {
            #pragma unroll
            for (int rloc = 0; rloc < 8; ++rloc) {
                #pragma unroll
                for (int g = 0; g < 4; ++g) {
                    f4 v;
                    v.x = acc[rloc][4*g+0]; v.y = acc[rloc][4*g+1];
                    v.z = acc[rloc][4*g+2]; v.w = acc[rloc][4*g+3];
                    int point = (R + rloc)*32 + 8*g + mb4;   // m rows 8g+mb4+0..3
                    *(f4*)&obuf[n*OB_STRIDE + point] = v;
                }
            }
        }
    }
    __syncthreads();
    {
        int p0 = tid * 4;
        f4 vals[8];
        #pragma unroll
        for (int n = 0; n < 8; ++n)
            vals[n] = *(const f4*)&obuf[n*OB_STRIDE + p0];
        unsigned mword = *(const unsigned*)&msk[p0];
        f4 r4;
        #pragma unroll
        for (int q = 0; q < 4; ++q) {
            unsigned nib = (mword >> (8*q)) & 0xFu;
            float res = 0.f;
            #pragma unroll
            for (int i = 0; i < 4; ++i) {          // i = s1*2+s2
                float s0 = __builtin_amdgcn_rcpf(1.f + __expf(-vals[2*i][q]));
                float s1 = __builtin_amdgcn_rcpf(1.f + __expf(-vals[2*i+1][q]));
                float m  = ((nib >> i) & 1u) ? 1.f : 0.f;
                res = fmaf(m, s0 + s1, res);
            }
            r4[q] = res;
        }
        *(f4*)(out + blockbase + p0) = r4;
    }
}

// ---------------------------------------------------------------------------
// fp32 fallback (ws too small): known-good from round 1.
// ---------------------------------------------------------------------------
__global__ void build_wtab(const float* __restrict__ w, float* __restrict__ tab) {
    int idx = blockIdx.x * blockDim.x + threadIdx.x;
    if (idx >= TAB_ELEMS) return;
    int n  = idx & 7;
    int r  = idx >> 3;
    int p5 = r % 3; r /= 3;
    int p4 = r % 3; r /= 3;
    int p3 = r % 3; r /= 3;
    int p2 = r % 3; r /= 3;
    int t  = r;
    int t1 = t >> 1, t2 = t & 1;
    int br = n & 1;
    int s  = n >> 1;
    int s1 = s >> 1, s2 = s & 1;
    int a = t1 - s1 + 1;
    int b = t2 - s2 + 1;
    int widx = (br == 0)
        ? (a*243 + b*81 + p2*27 + p3*9 + p4*3 + p5)
        : (b*243 + a*81 + p4*27 + p5*9 + p2*3 + p3);
    tab[idx] = w[widx];
}

__global__ __launch_bounds__(256)
void conv_fp32(const float* __restrict__ x,
               const float* __restrict__ tab,
               float* __restrict__ out) {
    const int e4 = threadIdx.x;
    const int e3 = blockIdx.x * 8 + threadIdx.y;
    const int e2 = blockIdx.y;
    const int e1 = blockIdx.z;

    float acc[8];
    #pragma unroll
    for (int n = 0; n < 8; ++n) acc[n] = 0.f;

    #pragma unroll 1
    for (int t = 0; t < 4; ++t) {
        const float* st  = x + (size_t)t * X_SLAB;
        const float* wt0 = tab + t * 648;
        #pragma unroll
        for (int p2 = 0; p2 < 3; ++p2) {
            #pragma unroll
            for (int p3 = 0; p3 < 3; ++p3) {
                int i1 = e1 + p2 - 1, i2 = e2 + p3 - 1;
                bool v12 = ((unsigned)i1 < 32u) && ((unsigned)i2 < 32u);
                const float* base = st + (i1*32768 + i2*1024 + (e3-1)*32 + (e4-1));
                const float* wt = wt0 + (p2*3 + p3) * 72;
                #pragma unroll
                for (int p4 = 0; p4 < 3; ++p4) {
                    int i3 = e3 + p4 - 1;
                    bool v3 = v12 && ((unsigned)i3 < 32u);
                    #pragma unroll
                    for (int p5 = 0; p5 < 3; ++p5) {
                        int i4 = e4 + p5 - 1;
                        bool ok = v3 && ((unsigned)i4 < 32u);
                        float v = ok ? fmaxf(base[p4*32 + p5], 0.f) : 0.f;
                        const float* w8 = wt + (p4*3 + p5)*8;
                        #pragma unroll
                        for (int n = 0; n < 8; ++n)
                            acc[n] = fmaf(w8[n], v, acc[n]);
                    }
                }
            }
        }
    }

    const size_t eflat = (size_t)e1*32768 + e2*1024 + e3*32 + e4;
    float res = 0.f;
    #pragma unroll
    for (int i = 0; i < 4; ++i) {
        float xv = x[(size_t)i * X_SLAB + eflat];
        float s0 = __builtin_amdgcn_rcpf(1.f + __expf(-acc[2*i]));
        float s1 = __builtin_amdgcn_rcpf(1.f + __expf(-acc[2*i+1]));
        float m  = (xv != 0.f) ? 1.f : 0.f;
        res = fmaf(m, s0 + s1, res);
    }
    out[eflat] = res;
}

// ---------------------------------------------------------------------------
extern "C" void kernel_launch(void* const* d_in, const int* in_sizes, int n_in,
                              void* d_out, int out_size, void* d_ws, size_t ws_size,
                              hipStream_t stream) {
    const float* x = (const float*)d_in[0];    // (1,2,2,32,32,32,32) fp32
    const float* w = (const float*)d_in[1];    // (729,) fp32
    float* out = (float*)d_out;                // (1,32,32,32,32) fp32

    const size_t need = (size_t)RPT_OFF + (size_t)RPT_SITES*8ull + RPT_SLACK;

    if (ws_size >= need) {
        _Float16* tabm = (_Float16*)d_ws;                     // 27648 B
        ull*      rpt  = (ull*)((char*)d_ws + RPT_OFF);
        prep<<<dim3((RPT_SITES + 255)/256), dim3(256), 0, stream>>>(x, w, rpt, tabm);
        dim3 grd(32, 32, 1), blk(256, 1, 1);
        conv_mfma<<<grd, blk, 0, stream>>>(x, rpt, tabm, out);
    } else {
        float* tab = (float*)d_ws;
        build_wtab<<<dim3((TAB_ELEMS + 255)/256), dim3(256), 0, stream>>>(w, tab);
        dim3 blk(32, 8, 1), grd(4, 32, 32);
        conv_fp32<<<grd, blk, 0, stream>>>(x, tab, out);
    }
}

// Round 6
// 104.188 us; speedup vs baseline: 2.8898x; 1.0254x over previous
//
#include <hip/hip_runtime.h>

typedef _Float16 half8 __attribute__((ext_vector_type(8)));
typedef float f16v __attribute__((ext_vector_type(16)));
typedef float f4 __attribute__((ext_vector_type(4)));
typedef unsigned long long ull;

#define X_SLAB   1048576            // 32^4
#define PLANE_BYTES (34*36*4*2)     // 9792: one (j1,j2) plane [j3<34][j4<36][t<4] f16
#define RPT_SITES (34*34*34*36)     // 1,414,944 sites (8B each)
#define RPT_OFF  65536              // byte offset of rp_t in ws (tab before it)
#define RPT_SLACK 4096              // DMA tail overrun slack
#define TAB_N    (3*6*3*512)        // 27648 f16 entries
#define TAB_ELEMS  (4*81*8)         // fp32 fallback table

// ---------------------------------------------------------------------------
// prep: t-innermost padded relu f16 array; block 0 also builds the MFMA
// B-operand table (d2-packed: all 32 N columns used).
// rpt site (j1,j2,j3,j4) holds {relu(x[t][j-1])}_{t=0..3} (8B), zero in halo.
// tabm[p2][j2rel][p4][lane][j]: col n32=lane&31 -> d2=n32>>3, n8=n32&7;
// k=8*(lane>>5)+j -> p5h=k>>2, t=k&3; p3 = j2rel-d2 (valid 0..2 else 0).
// branch0: w[a',b',p2,p3,p4,p5]; branch1: w[b',a',p4,p5,p2,p3];
// a'=t1-s1+1, b'=t2-s2+1, n8=(s1*2+s2)*2+branch.
// ---------------------------------------------------------------------------
__global__ __launch_bounds__(256)
void prep(const float* __restrict__ x, const float* __restrict__ w,
          ull* __restrict__ rpt, _Float16* __restrict__ tabm) {
    unsigned s = blockIdx.x * 256 + threadIdx.x;
    if (s < RPT_SITES) {
        unsigned q = s;
        int j4 = q % 36; q /= 36;
        int j3 = q % 34; q /= 34;
        int j2 = q % 34; q /= 34;
        int j1 = q;
        union { _Float16 h[4]; ull u; } pk;
        pk.u = 0ull;
        if (j1 >= 1 && j1 <= 32 && j2 >= 1 && j2 <= 32 &&
            j3 >= 1 && j3 <= 32 && j4 >= 1 && j4 <= 32) {
            size_t off = (size_t)(j1-1)*32768 + (j2-1)*1024 + (j3-1)*32 + (j4-1);
            #pragma unroll
            for (int t = 0; t < 4; ++t)
                pk.h[t] = (_Float16)fmaxf(x[(size_t)t*X_SLAB + off], 0.f);
        }
        rpt[s] = pk.u;
    }
    if (blockIdx.x == 0) {
        for (int idx = threadIdx.x; idx < TAB_N; idx += 256) {
            int j = idx & 7, l = (idx >> 3) & 63, slice = idx >> 9;   // slice<54
            int p4 = slice % 3, j2rel = (slice/3) % 6, p2 = slice/18;
            int n32 = l & 31;
            int d2 = n32 >> 3, n8 = n32 & 7;
            int k = 8*(l>>5) + j;
            int p5h = k >> 2, t = k & 3;
            int p3 = j2rel - d2;
            float val = 0.f;
            if (p5h < 3 && p3 >= 0 && p3 <= 2) {
                int br = n8 & 1, sc = n8 >> 1, s1 = sc >> 1, s2 = sc & 1;
                int t1 = t >> 1, t2 = t & 1;
                int a = t1 - s1 + 1, b = t2 - s2 + 1;
                int widx = (br == 0)
                    ? (a*243 + b*81 + p2*27 + p3*9 + p4*3 + p5h)
                    : (b*243 + a*81 + p4*27 + p5h*9 + p2*3 + p3);
                val = w[widx];
            }
            tabm[idx] = (_Float16)val;
        }
    }
}

// ---------------------------------------------------------------------------
// conv_mfma: block = (e2b=4*bx, e1=by); 4096 points (4 e2 x 32 e3 x 32 e4).
// Wave wv owns e3-rows 8wv..8wv+7. 18 staged planes (p2 x j2rel), double-
// buffered LDS DMA + B-register prefetch. One A-load feeds 3 p4 MFMAs.
// Epilogue: sigmoid+mask per element, shfl_xor butterfly over n8, f4 stores.
// ---------------------------------------------------------------------------
__global__ __launch_bounds__(256)
void conv_mfma(const float* __restrict__ x, const ull* __restrict__ rpt,
               const _Float16* __restrict__ tabm, float* __restrict__ out) {
    __shared__ __align__(16) unsigned char arena[2*12288 + 4096];
    unsigned char* msk = arena + 24576;            // 4096 nibbles

    const int tid  = threadIdx.x;
    const int lane = tid & 63;
    const int wv   = tid >> 6;                     // 0..3
    const int e2b  = blockIdx.x * 4;
    const int e1   = blockIdx.y;
    const size_t blockbase = (size_t)e1*32768 + (size_t)e2b*1024;

    // mask nibbles: msk[dp] bit i = (x[i][blockbase+dp] != 0), dp in [0,4096)
    {
        int p0 = tid * 16;
        #pragma unroll
        for (int g = 0; g < 4; ++g) {
            f4 a0 = *(const f4*)(x + (size_t)0*X_SLAB + blockbase + p0 + 4*g);
            f4 a1 = *(const f4*)(x + (size_t)1*X_SLAB + blockbase + p0 + 4*g);
            f4 a2 = *(const f4*)(x + (size_t)2*X_SLAB + blockbase + p0 + 4*g);
            f4 a3 = *(const f4*)(x + (size_t)3*X_SLAB + blockbase + p0 + 4*g);
            unsigned wbits = 0;
            #pragma unroll
            for (int q = 0; q < 4; ++q) {
                unsigned b = (a0[q] != 0.f ? 1u : 0u) | (a1[q] != 0.f ? 2u : 0u)
                           | (a2[q] != 0.f ? 4u : 0u) | (a3[q] != 0.f ? 8u : 0u);
                wbits |= b << (8*q);
            }
            *(unsigned*)&msk[p0 + 4*g] = wbits;
        }
    }

    f16v acc[8];
    #pragma unroll
    for (int r = 0; r < 8; ++r)
        #pragma unroll
        for (int i = 0; i < 16; ++i) acc[r][i] = 0.f;

    const int R   = wv * 8;
    const int j4b = (lane & 31) + 2*(lane >> 5);   // A-frag site base

    // --- staged pipeline over 18 (p2, j2rel) planes, double-buffered ---
    half8 Bn[3];
    {   // stage plane 0 into buf 0, prefetch B(0)
        const char* pgb = (const char*)rpt + ((size_t)(e1+0)*34 + (e2b+0))*PLANE_BYTES;
        #pragma unroll
        for (int kk = 0; kk < 3; ++kk) {
            int off = (tid + kk*256) * 16;
            __builtin_amdgcn_global_load_lds(
                (const __attribute__((address_space(1))) unsigned int*)(pgb + off),
                (__attribute__((address_space(3))) unsigned int*)(arena + off),
                16, 0, 0);
        }
        const _Float16* tb = tabm + lane*8;
        Bn[0] = *(const half8*)(tb);
        Bn[1] = *(const half8*)(tb + 512);
        Bn[2] = *(const half8*)(tb + 1024);
    }

    #pragma unroll 1
    for (int it = 0; it < 18; ++it) {
        const int buf = it & 1;
        __syncthreads();                 // DMA(it) + B(it) loads complete
        half8 B0 = Bn[0], B1 = Bn[1], B2 = Bn[2];
        if (it + 1 < 18) {
            const int nit = it + 1;
            const int p2 = nit / 6, j2 = nit % 6;
            const char* pgb = (const char*)rpt
                            + ((size_t)(e1+p2)*34 + (e2b+j2)) * PLANE_BYTES;
            char* dst = (char*)arena + (buf^1)*12288;
            #pragma unroll
            for (int kk = 0; kk < 3; ++kk) {
                int off = (tid + kk*256) * 16;
                __builtin_amdgcn_global_load_lds(
                    (const __attribute__((address_space(1))) unsigned int*)(pgb + off),
                    (__attribute__((address_space(3))) unsigned int*)(dst + off),
                    16, 0, 0);
            }
            const _Float16* tb = tabm + (size_t)nit*1536 + lane*8;
            Bn[0] = *(const half8*)(tb);
            Bn[1] = *(const half8*)(tb + 512);
            Bn[2] = *(const half8*)(tb + 1024);
        }
        const _Float16* planeh = (const _Float16*)(arena + buf*12288);
        #pragma unroll
        for (int j3l = 0; j3l < 10; ++j3l) {
            const ull* ap = (const ull*)(planeh + ((R + j3l)*36 + j4b)*4);
            union { ull u[2]; half8 h; } A;
            A.u[0] = ap[0]; A.u[1] = ap[1];
            if (j3l <= 7)
                acc[j3l]   = __builtin_amdgcn_mfma_f32_32x32x16_f16(A.h, B0, acc[j3l],   0,0,0);
            if (j3l >= 1 && j3l <= 8)
                acc[j3l-1] = __builtin_amdgcn_mfma_f32_32x32x16_f16(A.h, B1, acc[j3l-1], 0,0,0);
            if (j3l >= 2)
                acc[j3l-2] = __builtin_amdgcn_mfma_f32_32x32x16_f16(A.h, B2, acc[j3l-2], 0,0,0);
        }
    }

    // ---- epilogue ----
    // D layout: col n32 = lane&31 (d2 = n32>>3, n8 = n32&7),
    // row m(e4) = (reg&3) + 8*(reg>>2) + 4*(lane>>5)
    const int n8 = lane & 7;
    const int d2 = (lane >> 3) & 3;
    const int h  = lane >> 5;
    const int sbit = n8 >> 1;
    float* outp = out + blockbase + (size_t)d2*1024;
    #pragma unroll
    for (int rloc = 0; rloc < 8; ++rloc) {
        const int e3 = R + rloc;
        float v[16];
        #pragma unroll
        for (int g = 0; g < 4; ++g) {
            unsigned mw = *(const unsigned*)&msk[d2*1024 + e3*32 + 8*g + 4*h];
            #pragma unroll
            for (int j = 0; j < 4; ++j) {
                float a  = acc[rloc][4*g + j];
                float sg = __builtin_amdgcn_rcpf(1.f + __expf(-a));
                v[4*g+j] = ((mw >> (8*j + sbit)) & 1u) ? sg : 0.f;
            }
        }
        #pragma unroll
        for (int i = 0; i < 16; ++i) {
            v[i] += __shfl_xor(v[i], 1);
            v[i] += __shfl_xor(v[i], 2);
            v[i] += __shfl_xor(v[i], 4);
        }
        if (n8 == 0) {
            #pragma unroll
            for (int g = 0; g < 4; ++g) {
                f4 o; o.x = v[4*g]; o.y = v[4*g+1]; o.z = v[4*g+2]; o.w = v[4*g+3];
                *(f4*)(outp + e3*32 + 8*g + 4*h) = o;
            }
        }
    }
}

// ---------------------------------------------------------------------------
// fp32 fallback (ws too small): known-good from round 1.
// ---------------------------------------------------------------------------
__global__ void build_wtab(const float* __restrict__ w, float* __restrict__ tab) {
    int idx = blockIdx.x * blockDim.x + threadIdx.x;
    if (idx >= TAB_ELEMS) return;
    int n  = idx & 7;
    int r  = idx >> 3;
    int p5 = r % 3; r /= 3;
    int p4 = r % 3; r /= 3;
    int p3 = r % 3; r /= 3;
    int p2 = r % 3; r /= 3;
    int t  = r;
    int t1 = t >> 1, t2 = t & 1;
    int br = n & 1;
    int s  = n >> 1;
    int s1 = s >> 1, s2 = s & 1;
    int a = t1 - s1 + 1;
    int b = t2 - s2 + 1;
    int widx = (br == 0)
        ? (a*243 + b*81 + p2*27 + p3*9 + p4*3 + p5)
        : (b*243 + a*81 + p4*27 + p5*9 + p2*3 + p3);
    tab[idx] = w[widx];
}

__global__ __launch_bounds__(256)
void conv_fp32(const float* __restrict__ x,
               const float* __restrict__ tab,
               float* __restrict__ out) {
    const int e4 = threadIdx.x;
    const int e3 = blockIdx.x * 8 + threadIdx.y;
    const int e2 = blockIdx.y;
    const int e1 = blockIdx.z;

    float acc[8];
    #pragma unroll
    for (int n = 0; n < 8; ++n) acc[n] = 0.f;

    #pragma unroll 1
    for (int t = 0; t < 4; ++t) {
        const float* st  = x + (size_t)t * X_SLAB;
        const float* wt0 = tab + t * 648;
        #pragma unroll
        for (int p2 = 0; p2 < 3; ++p2) {
            #pragma unroll
            for (int p3 = 0; p3 < 3; ++p3) {
                int i1 = e1 + p2 - 1, i2 = e2 + p3 - 1;
                bool v12 = ((unsigned)i1 < 32u) && ((unsigned)i2 < 32u);
                const float* base = st + (i1*32768 + i2*1024 + (e3-1)*32 + (e4-1));
                const float* wt = wt0 + (p2*3 + p3) * 72;
                #pragma unroll
                for (int p4 = 0; p4 < 3; ++p4) {
                    int i3 = e3 + p4 - 1;
                    bool v3 = v12 && ((unsigned)i3 < 32u);
                    #pragma unroll
                    for (int p5 = 0; p5 < 3; ++p5) {
                        int i4 = e4 + p5 - 1;
                        bool ok = v3 && ((unsigned)i4 < 32u);
                        float v = ok ? fmaxf(base[p4*32 + p5], 0.f) : 0.f;
                        const float* w8 = wt + (p4*3 + p5)*8;
                        #pragma unroll
                        for (int n = 0; n < 8; ++n)
                            acc[n] = fmaf(w8[n], v, acc[n]);
                    }
                }
            }
        }
    }

    const size_t eflat = (size_t)e1*32768 + e2*1024 + e3*32 + e4;
    float res = 0.f;
    #pragma unroll
    for (int i = 0; i < 4; ++i) {
        float xv = x[(size_t)i * X_SLAB + eflat];
        float s0 = __builtin_amdgcn_rcpf(1.f + __expf(-acc[2*i]));
        float s1 = __builtin_amdgcn_rcpf(1.f + __expf(-acc[2*i+1]));
        float m  = (xv != 0.f) ? 1.f : 0.f;
        res = fmaf(m, s0 + s1, res);
    }
    out[eflat] = res;
}

// ---------------------------------------------------------------------------
extern "C" void kernel_launch(void* const* d_in, const int* in_sizes, int n_in,
                              void* d_out, int out_size, void* d_ws, size_t ws_size,
                              hipStream_t stream) {
    const float* x = (const float*)d_in[0];    // (1,2,2,32,32,32,32) fp32
    const float* w = (const float*)d_in[1];    // (729,) fp32
    float* out = (float*)d_out;                // (1,32,32,32,32) fp32

    const size_t need = (size_t)RPT_OFF + (size_t)RPT_SITES*8ull + RPT_SLACK;

    if (ws_size >= need) {
        _Float16* tabm = (_Float16*)d_ws;                     // 55296 B
        ull*      rpt  = (ull*)((char*)d_ws + RPT_OFF);
        prep<<<dim3((RPT_SITES + 255)/256), dim3(256), 0, stream>>>(x, w, rpt, tabm);
        dim3 grd(8, 32, 1), blk(256, 1, 1);
        conv_mfma<<<grd, blk, 0, stream>>>(x, rpt, tabm, out);
    } else {
        float* tab = (float*)d_ws;
        build_wtab<<<dim3((TAB_ELEMS + 255)/256), dim3(256), 0, stream>>>(w, tab);
        dim3 blk(32, 8, 1), grd(4, 32, 32);
        conv_fp32<<<grd, blk, 0, stream>>>(x, tab, out);
    }
}